// Round 8
// baseline (678.811 us; speedup 1.0000x reference)
//
#include <hip/hip_runtime.h>
#include <hip/hip_bf16.h>

// SolveGradientsLST via two-level bucket binning + LDS accumulation.
// (3rd submission of the R6 design — infra failed twice; never executed.)
//
// R5 measured: total 664us; bucket_accum_solve = 475us (72%) with FETCH
// 675MB, VALUBusy 1.58%, WRITE ~0 -> gather-LATENCY-bound: each edge's
// pos[c]/field[c] hits 2 cache lines in 2 tables, ~1 request in flight per
// thread. KC changes under test:
//   * packed 32B node records (pos+field in ONE line)  -> halve random lines
//   * 4-wide manual unroll (all gathers issued before ds_adds) -> 4x MLP
// Fallback (ws too small for packed table): unroll-only variant, distinct
// kernel name so the profile reveals which path ran.

#define GRAD_LIMIT 30000.0f
#define EPS 1e-8

#define NBUCKET_MAX 1024
#define BSHIFT 9
#define BSIZE 512                 // nodes per bucket
#define CHUNK 8192                // edges per block in KA/KB
#define BTHREADS 512
#define PER_THREAD (CHUNK / BTHREADS)   // 16
#define ACC_STRIDE 13             // 11 used + 2 pad; gcd(13,32)=1 spreads banks

// ---------------- KP: build packed 32B node records ----------------
__global__ void pack_kernel(const float2* __restrict__ pos,
                            const float4* __restrict__ field,
                            float4* __restrict__ packed, int N) {
    int n = blockIdx.x * blockDim.x + threadIdx.x;
    if (n >= N) return;
    float2 p = pos[n];
    float4 f = field[n];
    packed[2 * n + 0] = make_float4(p.x, p.y, f.x, f.y);
    packed[2 * n + 1] = make_float4(f.z, f.w, 0.f, 0.f);
}

// ---------------- KA: bucket histogram (LDS-aggregated) ----------------
__global__ void __launch_bounds__(BTHREADS)
bucket_count_kernel(const int* __restrict__ rows, int* __restrict__ bucket_cnt,
                    int E, int nbuckets) {
    __shared__ int hist[NBUCKET_MAX];
    for (int i = threadIdx.x; i < nbuckets; i += blockDim.x) hist[i] = 0;
    __syncthreads();

    int base = blockIdx.x * CHUNK;
    int lim = E - base;
    if (lim > CHUNK) lim = CHUNK;
    for (int k = threadIdx.x; k < lim; k += blockDim.x) {
        int r = rows[base + k];
        atomicAdd(&hist[r >> BSHIFT], 1);
    }
    __syncthreads();
    for (int i = threadIdx.x; i < nbuckets; i += blockDim.x) {
        int c = hist[i];
        if (c) atomicAdd(&bucket_cnt[i], c);   // fire-and-forget
    }
}

// ---------------- KS: single-block scan of bucket counts ----------------
__global__ void bucket_scan_kernel(const int* __restrict__ bucket_cnt,
                                   int* __restrict__ bucket_start,
                                   int* __restrict__ cursor, int nb) {
    __shared__ int s[NBUCKET_MAX];
    int t = threadIdx.x;
    int v = (t < nb) ? bucket_cnt[t] : 0;
    s[t] = v;
    __syncthreads();
    for (int d = 1; d < NBUCKET_MAX; d <<= 1) {
        int x = (t >= d) ? s[t - d] : 0;
        __syncthreads();
        s[t] += x;
        __syncthreads();
    }
    if (t < nb) {
        int ex = s[t] - v;     // exclusive prefix
        bucket_start[t] = ex;
        cursor[t] = ex;
    }
}

// ---------------- KB: scatter packed payload into bucket regions --------
__global__ void __launch_bounds__(BTHREADS)
bucket_scatter_kernel(const int* __restrict__ rows, const int* __restrict__ cols,
                      int* __restrict__ cursor, unsigned* __restrict__ payload,
                      int E, int nbuckets) {
    __shared__ int hist[NBUCKET_MAX];
    __shared__ int lbase[NBUCKET_MAX];
    for (int i = threadIdx.x; i < nbuckets; i += blockDim.x) hist[i] = 0;
    __syncthreads();

    int base = blockIdx.x * CHUNK;
    int lim = E - base;
    if (lim > CHUNK) lim = CHUNK;

    unsigned pk[PER_THREAD];
    int bl[PER_THREAD];   // (bucket<<13)|local_rank, or -1 if inactive
#pragma unroll
    for (int k = 0; k < PER_THREAD; ++k) {
        int idx = k * BTHREADS + threadIdx.x;   // coalesced per iteration
        if (idx < lim) {
            int e = base + idx;
            int r = rows[e];
            int c = cols[e];
            int b = r >> BSHIFT;
            int lr = atomicAdd(&hist[b], 1);    // LDS returning atomic (fast)
            pk[k] = ((unsigned)(r & (BSIZE - 1)) << 19) | (unsigned)c;  // c<2^19
            bl[k] = (b << 13) | lr;             // lr < 8192
        } else {
            bl[k] = -1;
        }
    }
    __syncthreads();
    // One returning global atomic per (block, nonzero bucket): ~1M total.
    for (int i = threadIdx.x; i < nbuckets; i += blockDim.x) {
        int c = hist[i];
        lbase[i] = c ? atomicAdd(&cursor[i], c) : 0;
    }
    __syncthreads();
#pragma unroll
    for (int k = 0; k < PER_THREAD; ++k) {
        if (bl[k] >= 0) {
            int b = bl[k] >> 13;
            int lr = bl[k] & 8191;
            payload[lbase[b] + lr] = pk[k];     // ~32B contiguous runs
        }
    }
}

// Per-edge accumulate into LDS from packed records.
#define EDGE_ACCUM(ca, cb, ra, rb, rl) do {                                   \
        float dx0 = (ca).x - (ra).x;                                          \
        float dx1 = (ca).y - (ra).y;                                          \
        float du0 = (ca).z - (ra).z;                                          \
        float du1 = (ca).w - (ra).w;                                          \
        float du2 = (cb).x - (rb).x;                                          \
        float du3 = (cb).y - (rb).y;                                          \
        float* ap = acc + (rl) * ACC_STRIDE;                                  \
        atomicAdd(ap + 0, dx0 * dx0);                                         \
        atomicAdd(ap + 1, dx0 * dx1);                                         \
        atomicAdd(ap + 2, dx1 * dx1);                                         \
        atomicAdd(ap + 3, dx0 * du0);                                         \
        atomicAdd(ap + 4, dx0 * du1);                                         \
        atomicAdd(ap + 5, dx0 * du2);                                         \
        atomicAdd(ap + 6, dx0 * du3);                                         \
        atomicAdd(ap + 7, dx1 * du0);                                         \
        atomicAdd(ap + 8, dx1 * du1);                                         \
        atomicAdd(ap + 9, dx1 * du2);                                         \
        atomicAdd(ap + 10, dx1 * du3);                                        \
    } while (0)

// Per-edge accumulate from two-table (pos/field) gathers.
#define EDGE_ACCUM2(pc, pr, fc, fr, rl) do {                                  \
        float dx0 = (pc).x - (pr).x;                                          \
        float dx1 = (pc).y - (pr).y;                                          \
        float du0 = (fc).x - (fr).x;                                          \
        float du1 = (fc).y - (fr).y;                                          \
        float du2 = (fc).z - (fr).z;                                          \
        float du3 = (fc).w - (fr).w;                                          \
        float* ap = acc + (rl) * ACC_STRIDE;                                  \
        atomicAdd(ap + 0, dx0 * dx0);                                         \
        atomicAdd(ap + 1, dx0 * dx1);                                         \
        atomicAdd(ap + 2, dx1 * dx1);                                         \
        atomicAdd(ap + 3, dx0 * du0);                                         \
        atomicAdd(ap + 4, dx0 * du1);                                         \
        atomicAdd(ap + 5, dx0 * du2);                                         \
        atomicAdd(ap + 6, dx0 * du3);                                         \
        atomicAdd(ap + 7, dx1 * du0);                                         \
        atomicAdd(ap + 8, dx1 * du1);                                         \
        atomicAdd(ap + 9, dx1 * du2);                                         \
        atomicAdd(ap + 10, dx1 * du3);                                        \
    } while (0)

// Shared epilogue: f64 2x2 solve + clip + transposed store.
__device__ __forceinline__ void solve_store(const float* acc, int node0, int N,
                                            float* out) {
    int rl = threadIdx.x;
    int n = node0 + rl;
    if (n >= N) return;
    const float* a = acc + rl * ACC_STRIDE;
    // f64 solve: f32 det = m00*m11 - m01^2 is cancellation-dominated for
    // low-degree nodes.
    double M00 = (double)a[0] + EPS;
    double M01 = (double)a[1];
    double M11 = (double)a[2] + EPS;
    double inv_det = 1.0 / (M00 * M11 - M01 * M01);
    double i00 = M11 * inv_det;
    double i01 = -M01 * inv_det;
    double i11 = M00 * inv_det;
    const float vf0[4] = {a[3], a[4], a[5], a[6]};
    const float vf1[4] = {a[7], a[8], a[9], a[10]};
#pragma unroll
    for (int f = 0; f < 4; ++f) {
        float ga = (float)(i00 * (double)vf0[f] + i01 * (double)vf1[f]);
        float gb = (float)(i01 * (double)vf0[f] + i11 * (double)vf1[f]);
        float2 o;
        o.x = fminf(fmaxf(ga, -GRAD_LIMIT), GRAD_LIMIT);
        o.y = fminf(fmaxf(gb, -GRAD_LIMIT), GRAD_LIMIT);
        *reinterpret_cast<float2*>(out + (size_t)f * N * 2 + (size_t)n * 2) = o;
    }
}

// ---------------- KC primary: packed table + 4-wide unroll ----------------
__global__ void __launch_bounds__(BSIZE)
bucket_accum_solve_packed(const float4* __restrict__ packed,
                          const int* __restrict__ bucket_start,
                          const int* __restrict__ cursor,   // == bucket end
                          const unsigned* __restrict__ payload,
                          float* __restrict__ out,  // [F,N,2]
                          int N) {
    __shared__ float acc[BSIZE * ACC_STRIDE];   // 26.6 KB
    int b = blockIdx.x;
    int node0 = b << BSHIFT;

    for (int i = threadIdx.x; i < BSIZE * ACC_STRIDE; i += blockDim.x)
        acc[i] = 0.f;
    __syncthreads();

    int s1 = cursor[b];
    int i = bucket_start[b] + threadIdx.x;

    // 4-wide unrolled main loop: all loads issued before any ds_add.
    for (; i + 3 * BSIZE < s1; i += 4 * BSIZE) {
        unsigned p0 = payload[i];
        unsigned p1 = payload[i + BSIZE];
        unsigned p2 = payload[i + 2 * BSIZE];
        unsigned p3 = payload[i + 3 * BSIZE];
        int c0 = (int)(p0 & 0x7FFFFu), rl0 = (int)(p0 >> 19);
        int c1 = (int)(p1 & 0x7FFFFu), rl1 = (int)(p1 >> 19);
        int c2 = (int)(p2 & 0x7FFFFu), rl2 = (int)(p2 >> 19);
        int c3 = (int)(p3 & 0x7FFFFu), rl3 = (int)(p3 >> 19);
        float4 ca0 = packed[2 * c0], cb0 = packed[2 * c0 + 1];
        float4 ca1 = packed[2 * c1], cb1 = packed[2 * c1 + 1];
        float4 ca2 = packed[2 * c2], cb2 = packed[2 * c2 + 1];
        float4 ca3 = packed[2 * c3], cb3 = packed[2 * c3 + 1];
        float4 ra0 = packed[2 * (node0 + rl0)], rb0 = packed[2 * (node0 + rl0) + 1];
        float4 ra1 = packed[2 * (node0 + rl1)], rb1 = packed[2 * (node0 + rl1) + 1];
        float4 ra2 = packed[2 * (node0 + rl2)], rb2 = packed[2 * (node0 + rl2) + 1];
        float4 ra3 = packed[2 * (node0 + rl3)], rb3 = packed[2 * (node0 + rl3) + 1];
        EDGE_ACCUM(ca0, cb0, ra0, rb0, rl0);
        EDGE_ACCUM(ca1, cb1, ra1, rb1, rl1);
        EDGE_ACCUM(ca2, cb2, ra2, rb2, rl2);
        EDGE_ACCUM(ca3, cb3, ra3, rb3, rl3);
    }
    // tail
    for (; i < s1; i += BSIZE) {
        unsigned p = payload[i];
        int c = (int)(p & 0x7FFFFu), rl = (int)(p >> 19);
        float4 ca = packed[2 * c], cb = packed[2 * c + 1];
        float4 ra = packed[2 * (node0 + rl)], rb = packed[2 * (node0 + rl) + 1];
        EDGE_ACCUM(ca, cb, ra, rb, rl);
    }
    __syncthreads();
    solve_store(acc, node0, N, out);
}

// ---------------- KC fallback: two-table + 4-wide unroll -------------------
__global__ void __launch_bounds__(BSIZE)
bucket_accum_solve_unrolled(const float2* __restrict__ pos,
                            const float4* __restrict__ field,
                            const int* __restrict__ bucket_start,
                            const int* __restrict__ cursor,
                            const unsigned* __restrict__ payload,
                            float* __restrict__ out, int N) {
    __shared__ float acc[BSIZE * ACC_STRIDE];
    int b = blockIdx.x;
    int node0 = b << BSHIFT;
    for (int i = threadIdx.x; i < BSIZE * ACC_STRIDE; i += blockDim.x)
        acc[i] = 0.f;
    __syncthreads();

    int s1 = cursor[b];
    int i = bucket_start[b] + threadIdx.x;
    for (; i + 3 * BSIZE < s1; i += 4 * BSIZE) {
        unsigned p0 = payload[i];
        unsigned p1 = payload[i + BSIZE];
        unsigned p2 = payload[i + 2 * BSIZE];
        unsigned p3 = payload[i + 3 * BSIZE];
        int c0 = (int)(p0 & 0x7FFFFu), rl0 = (int)(p0 >> 19);
        int c1 = (int)(p1 & 0x7FFFFu), rl1 = (int)(p1 >> 19);
        int c2 = (int)(p2 & 0x7FFFFu), rl2 = (int)(p2 >> 19);
        int c3 = (int)(p3 & 0x7FFFFu), rl3 = (int)(p3 >> 19);
        float2 pc0 = pos[c0], pc1 = pos[c1], pc2 = pos[c2], pc3 = pos[c3];
        float4 fc0 = field[c0], fc1 = field[c1], fc2 = field[c2], fc3 = field[c3];
        float2 pr0 = pos[node0 + rl0], pr1 = pos[node0 + rl1];
        float2 pr2 = pos[node0 + rl2], pr3 = pos[node0 + rl3];
        float4 fr0 = field[node0 + rl0], fr1 = field[node0 + rl1];
        float4 fr2 = field[node0 + rl2], fr3 = field[node0 + rl3];
        EDGE_ACCUM2(pc0, pr0, fc0, fr0, rl0);
        EDGE_ACCUM2(pc1, pr1, fc1, fr1, rl1);
        EDGE_ACCUM2(pc2, pr2, fc2, fr2, rl2);
        EDGE_ACCUM2(pc3, pr3, fc3, fr3, rl3);
    }
    for (; i < s1; i += BSIZE) {
        unsigned p = payload[i];
        int c = (int)(p & 0x7FFFFu), rl = (int)(p >> 19);
        float2 pc = pos[c], pr = pos[node0 + rl];
        float4 fc = field[c], fr = field[node0 + rl];
        EDGE_ACCUM2(pc, pr, fc, fr, rl);
    }
    __syncthreads();
    solve_store(acc, node0, N, out);
}

extern "C" void kernel_launch(void* const* d_in, const int* in_sizes, int n_in,
                              void* d_out, int out_size, void* d_ws, size_t ws_size,
                              hipStream_t stream) {
    const float2* pos = (const float2*)d_in[0];
    const int* edge_index = (const int*)d_in[1];
    const float4* field = (const float4*)d_in[2];
    float* out = (float*)d_out;

    const int N = in_sizes[0] / 2;
    const int E = in_sizes[1] / 2;

    const int* rows = edge_index;      // edge_index[0, :]
    const int* cols = edge_index + E;  // edge_index[1, :]

    const int nbuckets = (N + BSIZE - 1) / BSIZE;       // 977
    const int nblocksE = (E + CHUNK - 1) / CHUNK;       // 977

    size_t packed_bytes = (size_t)2 * N * sizeof(float4);            // 16 MB
    size_t need_packed = packed_bytes + (size_t)3 * NBUCKET_MAX * 4
                         + (size_t)E * 4;                            // ~48 MB

    if (ws_size >= need_packed) {
        // Layout: packed[2N] f4 | cnt[1024] | start[1024] | cursor[1024] | payload[E]
        float4* packed = (float4*)d_ws;
        int* bucket_cnt = (int*)(packed + (size_t)2 * N);
        int* bucket_start = bucket_cnt + NBUCKET_MAX;
        int* cursor = bucket_start + NBUCKET_MAX;
        unsigned* payload = (unsigned*)(cursor + NBUCKET_MAX);

        hipMemsetAsync(bucket_cnt, 0, NBUCKET_MAX * sizeof(int), stream);
        pack_kernel<<<(N + 255) / 256, 256, 0, stream>>>(pos, field, packed, N);
        bucket_count_kernel<<<nblocksE, BTHREADS, 0, stream>>>(rows, bucket_cnt,
                                                               E, nbuckets);
        bucket_scan_kernel<<<1, NBUCKET_MAX, 0, stream>>>(bucket_cnt,
                                                          bucket_start, cursor,
                                                          nbuckets);
        bucket_scatter_kernel<<<nblocksE, BTHREADS, 0, stream>>>(rows, cols,
                                                                 cursor, payload,
                                                                 E, nbuckets);
        bucket_accum_solve_packed<<<nbuckets, BSIZE, 0, stream>>>(packed,
                                                                  bucket_start,
                                                                  cursor, payload,
                                                                  out, N);
    } else {
        // Fallback: two-table gathers, still 4-wide unrolled.
        int* bucket_cnt = (int*)d_ws;
        int* bucket_start = bucket_cnt + NBUCKET_MAX;
        int* cursor = bucket_start + NBUCKET_MAX;
        unsigned* payload = (unsigned*)(cursor + NBUCKET_MAX);

        hipMemsetAsync(bucket_cnt, 0, NBUCKET_MAX * sizeof(int), stream);
        bucket_count_kernel<<<nblocksE, BTHREADS, 0, stream>>>(rows, bucket_cnt,
                                                               E, nbuckets);
        bucket_scan_kernel<<<1, NBUCKET_MAX, 0, stream>>>(bucket_cnt,
                                                          bucket_start, cursor,
                                                          nbuckets);
        bucket_scatter_kernel<<<nblocksE, BTHREADS, 0, stream>>>(rows, cols,
                                                                 cursor, payload,
                                                                 E, nbuckets);
        bucket_accum_solve_unrolled<<<nbuckets, BSIZE, 0, stream>>>(pos, field,
                                                                    bucket_start,
                                                                    cursor, payload,
                                                                    out, N);
    }
}

// Round 10
// 340.591 us; speedup vs baseline: 1.9930x; 1.9930x over previous
//
#include <hip/hip_runtime.h>
#include <hip/hip_bf16.h>

// SolveGradientsLST via two-level bucket binning + within-bucket LDS counting
// sort + per-thread register accumulation.
// (Resubmission of R9 — GPU acquisition timed out; kernel never executed.)
//
// R8 measured: packed records halved FETCH (675->413MB) and 4-wide unroll
// raised MLP, yet KC duration was UNCHANGED (475->472us). KC is neither
// HBM-BW- nor MLP-latency-bound. Remaining candidates, both invariant across
// R5/R8: (a) divergent-VMEM tag path (4 divergent wave-loads/edge),
// (b) LDS f32-atomic pipe (11 ds_add_f32/edge). This KC eliminates the row
// gathers AND all f32 LDS atomics: sort the bucket's edges by local row in
// LDS, then each thread register-accumulates its own row's contiguous range.
//
// Pipeline:
//   KP  packed[n] = {pos, field} 32B records
//   KA  per-block LDS histogram of row>>9  -> ~1M global adds
//   KS  1-block scan of 977 bucket counts
//   KB  per-block LDS ranks + 1 returning global atomic per (block,bucket);
//       payload = (row&511)<<19 | col
//   KC  per bucket, chunks of <=10240 edges:
//         pass1 hist[512] (int ds_add), pass2 LDS scan + scatter to sorted[],
//         pass3 thread t drains row t: 2 divergent col-loads/edge,
//               register accumulate -> f64 solve -> [F,N,2]

#define GRAD_LIMIT 30000.0f
#define EPS 1e-8

#define NBUCKET_MAX 1024
#define BSHIFT 9
#define BSIZE 512                 // nodes per bucket == threads in KC
#define CHUNK 8192                // edges per block in KA/KB
#define BTHREADS 512
#define PER_THREAD (CHUNK / BTHREADS)   // 16
#define CAP 10240                 // sorted[] entries per KC chunk (40 KB)

// ---------------- KP: build packed 32B node records ----------------
__global__ void pack_kernel(const float2* __restrict__ pos,
                            const float4* __restrict__ field,
                            float4* __restrict__ packed, int N) {
    int n = blockIdx.x * blockDim.x + threadIdx.x;
    if (n >= N) return;
    float2 p = pos[n];
    float4 f = field[n];
    packed[2 * n + 0] = make_float4(p.x, p.y, f.x, f.y);
    packed[2 * n + 1] = make_float4(f.z, f.w, 0.f, 0.f);
}

// ---------------- KA: bucket histogram (LDS-aggregated) ----------------
__global__ void __launch_bounds__(BTHREADS)
bucket_count_kernel(const int* __restrict__ rows, int* __restrict__ bucket_cnt,
                    int E, int nbuckets) {
    __shared__ int hist[NBUCKET_MAX];
    for (int i = threadIdx.x; i < nbuckets; i += blockDim.x) hist[i] = 0;
    __syncthreads();

    int base = blockIdx.x * CHUNK;
    int lim = E - base;
    if (lim > CHUNK) lim = CHUNK;
    for (int k = threadIdx.x; k < lim; k += blockDim.x) {
        int r = rows[base + k];
        atomicAdd(&hist[r >> BSHIFT], 1);
    }
    __syncthreads();
    for (int i = threadIdx.x; i < nbuckets; i += blockDim.x) {
        int c = hist[i];
        if (c) atomicAdd(&bucket_cnt[i], c);   // fire-and-forget
    }
}

// ---------------- KS: single-block scan of bucket counts ----------------
__global__ void bucket_scan_kernel(const int* __restrict__ bucket_cnt,
                                   int* __restrict__ bucket_start,
                                   int* __restrict__ cursor, int nb) {
    __shared__ int s[NBUCKET_MAX];
    int t = threadIdx.x;
    int v = (t < nb) ? bucket_cnt[t] : 0;
    s[t] = v;
    __syncthreads();
    for (int d = 1; d < NBUCKET_MAX; d <<= 1) {
        int x = (t >= d) ? s[t - d] : 0;
        __syncthreads();
        s[t] += x;
        __syncthreads();
    }
    if (t < nb) {
        int ex = s[t] - v;     // exclusive prefix
        bucket_start[t] = ex;
        cursor[t] = ex;
    }
}

// ---------------- KB: scatter packed payload into bucket regions --------
__global__ void __launch_bounds__(BTHREADS)
bucket_scatter_kernel(const int* __restrict__ rows, const int* __restrict__ cols,
                      int* __restrict__ cursor, unsigned* __restrict__ payload,
                      int E, int nbuckets) {
    __shared__ int hist[NBUCKET_MAX];
    __shared__ int lbase[NBUCKET_MAX];
    for (int i = threadIdx.x; i < nbuckets; i += blockDim.x) hist[i] = 0;
    __syncthreads();

    int base = blockIdx.x * CHUNK;
    int lim = E - base;
    if (lim > CHUNK) lim = CHUNK;

    unsigned pk[PER_THREAD];
    int bl[PER_THREAD];   // (bucket<<13)|local_rank, or -1 if inactive
#pragma unroll
    for (int k = 0; k < PER_THREAD; ++k) {
        int idx = k * BTHREADS + threadIdx.x;   // coalesced per iteration
        if (idx < lim) {
            int e = base + idx;
            int r = rows[e];
            int c = cols[e];
            int b = r >> BSHIFT;
            int lr = atomicAdd(&hist[b], 1);    // LDS returning atomic (fast)
            pk[k] = ((unsigned)(r & (BSIZE - 1)) << 19) | (unsigned)c;  // c<2^19
            bl[k] = (b << 13) | lr;             // lr < 8192
        } else {
            bl[k] = -1;
        }
    }
    __syncthreads();
    // One returning global atomic per (block, nonzero bucket): ~1M total.
    for (int i = threadIdx.x; i < nbuckets; i += blockDim.x) {
        int c = hist[i];
        lbase[i] = c ? atomicAdd(&cursor[i], c) : 0;
    }
    __syncthreads();
#pragma unroll
    for (int k = 0; k < PER_THREAD; ++k) {
        if (bl[k] >= 0) {
            int b = bl[k] >> 13;
            int lr = bl[k] & 8191;
            payload[lbase[b] + lr] = pk[k];     // ~32B contiguous runs
        }
    }
}

// ---------------- KC: within-bucket row sort + register accumulation ----
__global__ void __launch_bounds__(BSIZE)
bucket_sort_accum_solve(const float4* __restrict__ packed,
                        const int* __restrict__ bucket_start,
                        const int* __restrict__ cursor,   // == bucket end
                        const unsigned* __restrict__ payload,
                        float* __restrict__ out,  // [F,N,2]
                        int N) {
    __shared__ unsigned sorted[CAP];   // 40 KB
    __shared__ int hist[BSIZE];        // 2 KB: per-row counts
    __shared__ int incl[BSIZE];        // 2 KB: inclusive scan
    __shared__ int cur[BSIZE];         // 2 KB: scatter cursor

    int t = threadIdx.x;
    int b = blockIdx.x;
    int node0 = b << BSHIFT;

    // Row record for this thread's node (one gather per THREAD, not per edge).
    float4 ra = make_float4(0.f, 0.f, 0.f, 0.f);
    float4 rb = ra;
    if (node0 + t < N) {
        ra = packed[2 * (node0 + t) + 0];
        rb = packed[2 * (node0 + t) + 1];
    }

    // Register accumulators (persist across chunks).
    float m00 = 0.f, m01 = 0.f, m11 = 0.f;
    float v00 = 0.f, v01 = 0.f, v02 = 0.f, v03 = 0.f;
    float v10 = 0.f, v11 = 0.f, v12 = 0.f, v13 = 0.f;

    int s0 = bucket_start[b];
    int s1 = cursor[b];

    for (int cstart = s0; cstart < s1; cstart += CAP) {
        int cnt = s1 - cstart;
        if (cnt > CAP) cnt = CAP;

        hist[t] = 0;
        __syncthreads();

        // pass1: coalesced histogram of local rows
        for (int i = t; i < cnt; i += BSIZE) {
            unsigned p = payload[cstart + i];
            atomicAdd(&hist[p >> 19], 1);
        }
        __syncthreads();

        // scan: inclusive Hillis-Steele over 512 entries
        incl[t] = hist[t];
        __syncthreads();
        for (int d = 1; d < BSIZE; d <<= 1) {
            int x = (t >= d) ? incl[t - d] : 0;
            __syncthreads();
            incl[t] += x;
            __syncthreads();
        }
        cur[t] = incl[t] - hist[t];   // exclusive start
        __syncthreads();

        // pass2: scatter into row-sorted LDS order
        for (int i = t; i < cnt; i += BSIZE) {
            unsigned p = payload[cstart + i];
            int k = atomicAdd(&cur[p >> 19], 1);
            sorted[k] = p;
        }
        __syncthreads();

        // pass3: thread t drains row t's contiguous range; col gathers only
        int st = incl[t] - hist[t];
        int en = incl[t];
        for (int k = st; k < en; ++k) {
            unsigned p = sorted[k];
            int c = (int)(p & 0x7FFFFu);
            float4 ca = packed[2 * c + 0];
            float4 cb = packed[2 * c + 1];
            float dx0 = ca.x - ra.x;
            float dx1 = ca.y - ra.y;
            float du0 = ca.z - ra.z;
            float du1 = ca.w - ra.w;
            float du2 = cb.x - rb.x;
            float du3 = cb.y - rb.y;
            m00 = fmaf(dx0, dx0, m00);
            m01 = fmaf(dx0, dx1, m01);
            m11 = fmaf(dx1, dx1, m11);
            v00 = fmaf(dx0, du0, v00);
            v01 = fmaf(dx0, du1, v01);
            v02 = fmaf(dx0, du2, v02);
            v03 = fmaf(dx0, du3, v03);
            v10 = fmaf(dx1, du0, v10);
            v11 = fmaf(dx1, du1, v11);
            v12 = fmaf(dx1, du2, v12);
            v13 = fmaf(dx1, du3, v13);
        }
        __syncthreads();   // before next chunk overwrites LDS
    }

    // Epilogue: f64 2x2 solve (f32 det = m00*m11 - m01^2 is cancellation-
    // dominated for low-degree nodes), clip, transposed store.
    int n = node0 + t;
    if (n >= N) return;
    double M00 = (double)m00 + EPS;
    double M01 = (double)m01;
    double M11 = (double)m11 + EPS;
    double inv_det = 1.0 / (M00 * M11 - M01 * M01);
    double i00 = M11 * inv_det;
    double i01 = -M01 * inv_det;
    double i11 = M00 * inv_det;

    const float vf0[4] = {v00, v01, v02, v03};
    const float vf1[4] = {v10, v11, v12, v13};
#pragma unroll
    for (int f = 0; f < 4; ++f) {
        float ga = (float)(i00 * (double)vf0[f] + i01 * (double)vf1[f]);
        float gb = (float)(i01 * (double)vf0[f] + i11 * (double)vf1[f]);
        float2 o;
        o.x = fminf(fmaxf(ga, -GRAD_LIMIT), GRAD_LIMIT);
        o.y = fminf(fmaxf(gb, -GRAD_LIMIT), GRAD_LIMIT);
        *reinterpret_cast<float2*>(out + (size_t)f * N * 2 + (size_t)n * 2) = o;
    }
}

extern "C" void kernel_launch(void* const* d_in, const int* in_sizes, int n_in,
                              void* d_out, int out_size, void* d_ws, size_t ws_size,
                              hipStream_t stream) {
    const float2* pos = (const float2*)d_in[0];
    const int* edge_index = (const int*)d_in[1];
    const float4* field = (const float4*)d_in[2];
    float* out = (float*)d_out;

    const int N = in_sizes[0] / 2;
    const int E = in_sizes[1] / 2;

    const int* rows = edge_index;      // edge_index[0, :]
    const int* cols = edge_index + E;  // edge_index[1, :]

    const int nbuckets = (N + BSIZE - 1) / BSIZE;       // 977
    const int nblocksE = (E + CHUNK - 1) / CHUNK;       // 977

    // Layout: packed[2N] f4 | cnt[1024] | start[1024] | cursor[1024] | payload[E]
    // (R8 ran this path, so ws_size >= ~48MB is confirmed on this harness.)
    float4* packed = (float4*)d_ws;
    int* bucket_cnt = (int*)(packed + (size_t)2 * N);
    int* bucket_start = bucket_cnt + NBUCKET_MAX;
    int* cursor = bucket_start + NBUCKET_MAX;
    unsigned* payload = (unsigned*)(cursor + NBUCKET_MAX);

    hipMemsetAsync(bucket_cnt, 0, NBUCKET_MAX * sizeof(int), stream);
    pack_kernel<<<(N + 255) / 256, 256, 0, stream>>>(pos, field, packed, N);
    bucket_count_kernel<<<nblocksE, BTHREADS, 0, stream>>>(rows, bucket_cnt, E,
                                                           nbuckets);
    bucket_scan_kernel<<<1, NBUCKET_MAX, 0, stream>>>(bucket_cnt, bucket_start,
                                                      cursor, nbuckets);
    bucket_scatter_kernel<<<nblocksE, BTHREADS, 0, stream>>>(rows, cols, cursor,
                                                             payload, E, nbuckets);
    bucket_sort_accum_solve<<<nbuckets, BSIZE, 0, stream>>>(packed, bucket_start,
                                                            cursor, payload,
                                                            out, N);
}